// Round 15
// baseline (700.020 us; speedup 1.0000x reference)
//
#include <hip/hip_runtime.h>

#define NROWS 8192
#define TDIM 768
#define IDIM 1024
#define DDIM 1024
#define NEXP 8
#define GHID 512

typedef __attribute__((ext_vector_type(8))) short short8;
typedef __attribute__((ext_vector_type(4))) float f4;
typedef __attribute__((ext_vector_type(4))) unsigned short us4;

__device__ __forceinline__ unsigned short f2bf(float f) {
  union { float f; unsigned u; } v; v.f = f;
  unsigned r = v.u + 0x7FFF + ((v.u >> 16) & 1);
  return (unsigned short)(r >> 16);
}
__device__ __forceinline__ float bf2f(unsigned short u) {
  union { unsigned u; float f; } v; v.u = ((unsigned)u) << 16;
  return v.f;
}

__device__ __forceinline__ void gload16(const void* g, void* l) {
  __builtin_amdgcn_global_load_lds(
      (const __attribute__((address_space(1))) void*)g,
      (__attribute__((address_space(3))) void*)l, 16, 0, 0);
}

// ---------------- fp32 -> bf16 elementwise cast (vectorized) ----------------
__global__ __launch_bounds__(256) void cast_bf16_kernel(
    const float* __restrict__ src, unsigned short* __restrict__ dst, int n4) {
  int i = blockIdx.x * 256 + threadIdx.x;
  if (i < n4) {
    f4 v = ((const f4*)src)[i];
    us4 o;
    o[0] = f2bf(v[0]); o[1] = f2bf(v[1]); o[2] = f2bf(v[2]); o[3] = f2bf(v[3]);
    ((us4*)dst)[i] = o;
  }
}

// ------- fp32 [b][R][C] -> bf16 [b][C][R] transpose+cast, 64x64 tile, 16B stores ----
__global__ __launch_bounds__(256) void transpose_cast_kernel(
    const float* __restrict__ src, unsigned short* __restrict__ dst, int R, int C) {
  __shared__ float tile[64][65];
  size_t base = (size_t)blockIdx.z * R * C;
  int c0 = blockIdx.x * 64, r0 = blockIdx.y * 64;
  int tx = threadIdx.x & 63, ty = threadIdx.x >> 6;  // 64 x 4
#pragma unroll
  for (int j = 0; j < 64; j += 4)
    tile[ty + j][tx] = src[base + (size_t)(r0 + ty + j) * C + c0 + tx];
  __syncthreads();
  const int tid = threadIdx.x;
#pragma unroll
  for (int i = 0; i < 2; i++) {
    int row = i * 32 + (tid >> 3);
    int c8 = (tid & 7) * 8;
    short8 v;
#pragma unroll
    for (int u = 0; u < 8; u++) v[u] = (short)f2bf(tile[c8 + u][row]);
    *(short8*)&dst[base + (size_t)(c0 + row) * R + r0 + c8] = v;
  }
}

// ======== 256x256-tile bf16 TN GEMM, BK=32, 8 waves, dbuf 64KB -> 2 blocks/CU ========
// R14: dbuf retained (R12 lesson) + 2 blocks/CU (m114 cross-block overlap hides the
// per-tile drain). Swizzle for 64B rows: byte ^= ((row&3)<<4) -> 2-way (free).
// 2 phases/tile, 16 MFMA each; stage A(t+1)@P1, B(t+1)@P2; vmcnt(0) at P2 end
// (drain covered by the co-resident block). Epilogue n-innermost (R13 write-combine).
template <int SILU, int OUTBF, int COLMAJ>
__global__ __launch_bounds__(512, 1) void gemm256_kernel(
    const unsigned short* __restrict__ A, const unsigned short* __restrict__ BT,
    const float* __restrict__ bias, void* __restrict__ Cptr,
    int K, int lda, int ldb, int ldc,
    size_t sA, size_t sB, size_t sBias, size_t sC) {
  __shared__ __align__(16) char LDS[65536];  // buf0 {A 16K, B 16K}, buf1 @32768

  const unsigned short* Ab = A + (size_t)blockIdx.z * sA;
  const unsigned short* Bb = BT + (size_t)blockIdx.z * sB;
  const float* biasb = bias + (size_t)blockIdx.z * sBias;

  const int gx = gridDim.x, gy = gridDim.y;
  const int nwg = gx * gy;
  const int orig = blockIdx.y * gx + blockIdx.x;
  const int q = nwg >> 3, r = nwg & 7;
  const int xcd = orig & 7, idx = orig >> 3;
  const int wgid = (xcd < r ? xcd * (q + 1) : r * (q + 1) + (xcd - r) * q) + idx;
  const int bx = COLMAJ ? (wgid / gy) : (wgid % gx);
  const int by = COLMAJ ? (wgid % gy) : (wgid / gx);

  const int tid = threadIdx.x;
  const int wave = tid >> 6, lane = tid & 63;
  const int wm = wave >> 2, wn = wave & 3;  // 2x4 waves; per-wave 128x64
  const int row0 = by * 256, col0 = bx * 256;

  f4 acc[8][4] = {};

  // staging: 64B rows, 4 slots of 16B; swizzle byte ^= ((row&3)<<4)
  const int srow = tid >> 2;                                     // 0..127 per call
  const int scolg = ((tid & 3) << 4) ^ (((tid >> 2) & 3) << 4);  // pre-swizzled src col
  const size_t lda2 = (size_t)lda * 2, ldb2 = (size_t)ldb * 2;
  const char* Abytes = (const char*)Ab;
  const char* Bbytes = (const char*)Bb;
  const size_t aG = (size_t)(row0 + srow) * lda2 + scolg;
  const size_t bG = (size_t)(col0 + srow) * ldb2 + scolg;
  char* ldsw = LDS + wave * 1024;  // DMA adds lane*16; wave covers 16 rows (1KB)

  auto stageA = [&](int tt) {
    const size_t kb = (size_t)tt << 6;  // tt*32 elems *2B
    char* d = ldsw + ((tt & 1) << 15);
    gload16(Abytes + aG + kb, d);
    gload16(Abytes + aG + (size_t)128 * lda2 + kb, d + 8192);
  };
  auto stageB = [&](int tt) {
    const size_t kb = (size_t)tt << 6;
    char* d = ldsw + ((tt & 1) << 15) + 16384;
    gload16(Bbytes + bG + kb, d);
    gload16(Bbytes + bG + (size_t)128 * ldb2 + kb, d + 8192);
  };

  // read: row = base + sub*16 + (lane&15); byte = row*64 + (((lane>>4)<<4) ^ ((row&3)<<4))
  const int aBase = (wm * 128 + (lane & 15)) * 64;
  const int bBase = 16384 + (wn * 64 + (lane & 15)) * 64;
  const int ck0 = ((lane >> 4) << 4) ^ ((lane & 3) << 4);

  const int NT = K >> 5;

  // prologue: stage tile 0
  stageA(0); stageB(0);
  asm volatile("s_waitcnt vmcnt(0)" ::: "memory");
  __builtin_amdgcn_s_barrier();

  for (int t = 0; t < NT; t++) {
    const int buf = (t & 1) << 15;

    // ---- P1: read all B (4) + A m0..3 (4); stage A(t+1); 16 MFMA ----
    short8 bv[4];
    {
      short8 av[4];
#pragma unroll
      for (int n = 0; n < 4; n++)
        bv[n] = *(const short8*)(LDS + buf + bBase + n * 1024 + ck0);
#pragma unroll
      for (int m = 0; m < 4; m++)
        av[m] = *(const short8*)(LDS + buf + aBase + m * 1024 + ck0);
      if (t + 1 < NT) stageA(t + 1);
      __builtin_amdgcn_sched_barrier(0);
      __builtin_amdgcn_s_barrier();
      asm volatile("s_waitcnt lgkmcnt(0)" ::: "memory");
      __builtin_amdgcn_sched_barrier(0);
      __builtin_amdgcn_s_setprio(1);
#pragma unroll
      for (int m = 0; m < 4; m++)
#pragma unroll
        for (int n = 0; n < 4; n++)
          acc[m][n] = __builtin_amdgcn_mfma_f32_16x16x32_bf16(av[m], bv[n], acc[m][n], 0, 0, 0);
      __builtin_amdgcn_s_setprio(0);
      __builtin_amdgcn_s_barrier();
    }

    // ---- P2: read A m4..7 (4); stage B(t+1); 16 MFMA; vmcnt(0) ----
    {
      short8 av[4];
#pragma unroll
      for (int m = 0; m < 4; m++)
        av[m] = *(const short8*)(LDS + buf + aBase + (4 + m) * 1024 + ck0);
      if (t + 1 < NT) stageB(t + 1);
      __builtin_amdgcn_sched_barrier(0);
      __builtin_amdgcn_s_barrier();
      asm volatile("s_waitcnt lgkmcnt(0)" ::: "memory");
      __builtin_amdgcn_sched_barrier(0);
      __builtin_amdgcn_s_setprio(1);
#pragma unroll
      for (int m = 0; m < 4; m++)
#pragma unroll
        for (int n = 0; n < 4; n++)
          acc[4 + m][n] = __builtin_amdgcn_mfma_f32_16x16x32_bf16(av[m], bv[n], acc[4 + m][n], 0, 0, 0);
      __builtin_amdgcn_s_setprio(0);
      if (t + 1 < NT) {
        asm volatile("s_waitcnt vmcnt(0)" ::: "memory");  // t+1 resident; other block computes
      }
      __builtin_amdgcn_s_barrier();
    }
  }

  // epilogue: n innermost (write-combine, R13)
  const int crow0 = row0 + wm * 128 + (lane >> 4) * 4;
  const int ccol0 = col0 + wn * 64 + (lane & 15);
  char* Cb = (char*)Cptr + (size_t)blockIdx.z * sC * (OUTBF ? 2 : 4);
  float bvv[4];
#pragma unroll
  for (int n = 0; n < 4; n++) bvv[n] = biasb[ccol0 + n * 16];
#pragma unroll
  for (int m = 0; m < 8; m++) {
#pragma unroll
    for (int r2 = 0; r2 < 4; r2++) {
      const size_t rowb = (size_t)(crow0 + m * 16 + r2) * ldc;
#pragma unroll
      for (int n = 0; n < 4; n++) {
        float v = acc[m][n][r2] + bvv[n];
        if (SILU) v = v / (1.0f + __expf(-v));
        const size_t cidx = rowb + ccol0 + n * 16;
        if (OUTBF) ((unsigned short*)Cb)[cidx] = f2bf(v);
        else       ((float*)Cb)[cidx] = v;
      }
    }
  }
}

// ---------------- 128x128 m97-structure GEMM (gating) ----------------
template <int SILU, int OUTBF>
__global__ __launch_bounds__(256) void gemm_tn_kernel(
    const unsigned short* __restrict__ A, const unsigned short* __restrict__ BT,
    const float* __restrict__ bias, void* __restrict__ Cptr,
    int K, int lda, int ldb, int ldc,
    size_t sA, size_t sB, size_t sBias, size_t sC) {
  __shared__ unsigned short Als[128 * 32];
  __shared__ unsigned short Bls[128 * 32];

  const unsigned short* Ab = A + (size_t)blockIdx.z * sA;
  const unsigned short* Bb = BT + (size_t)blockIdx.z * sB;
  const float* biasb = bias + (size_t)blockIdx.z * sBias;

  const int gx = gridDim.x;
  const int nwg = gx * gridDim.y;
  const int orig = blockIdx.y * gx + blockIdx.x;
  const int q = nwg >> 3, r = nwg & 7;
  const int xcd = orig & 7, idx = orig >> 3;
  const int wgid = (xcd < r ? xcd * (q + 1) : r * (q + 1) + (xcd - r) * q) + idx;
  const int bx = wgid % gx, by = wgid / gx;

  const int tid = threadIdx.x;
  const int wave = tid >> 6, lane = tid & 63;
  const int row0 = by * 128, col0 = bx * 128;
  const int wm = wave >> 1, wn = wave & 1;
  f4 acc[4][4] = {};

  const int aoff = (wm * 64 + (lane & 15)) * 32 + (lane >> 4) * 8;
  const int boff = (wn * 64 + (lane & 15)) * 32 + (lane >> 4) * 8;

  const int L0 = tid, L1 = tid + 256;
  const size_t aofs0 = (size_t)(row0 + (L0 >> 2)) * lda + (L0 & 3) * 8;
  const size_t aofs1 = (size_t)(row0 + (L1 >> 2)) * lda + (L1 & 3) * 8;
  const size_t bofs0 = (size_t)(col0 + (L0 >> 2)) * ldb + (L0 & 3) * 8;
  const size_t bofs1 = (size_t)(col0 + (L1 >> 2)) * ldb + (L1 & 3) * 8;
  char* abase0 = (char*)Als + wave * 1024;
  char* abase1 = (char*)Als + 4096 + wave * 1024;
  char* bbase0 = (char*)Bls + wave * 1024;
  char* bbase1 = (char*)Bls + 4096 + wave * 1024;

  for (int k0 = 0; k0 < K; k0 += 32) {
    gload16(Ab + aofs0 + k0, abase0);
    gload16(Ab + aofs1 + k0, abase1);
    gload16(Bb + bofs0 + k0, bbase0);
    gload16(Bb + bofs1 + k0, bbase1);
    __syncthreads();
    short8 af[4], bfr[4];
#pragma unroll
    for (int i = 0; i < 4; i++) af[i] = *(const short8*)&Als[aoff + i * 512];
#pragma unroll
    for (int j = 0; j < 4; j++) bfr[j] = *(const short8*)&Bls[boff + j * 512];
#pragma unroll
    for (int i = 0; i < 4; i++)
#pragma unroll
      for (int j = 0; j < 4; j++)
        acc[i][j] = __builtin_amdgcn_mfma_f32_16x16x32_bf16(af[i], bfr[j], acc[i][j], 0, 0, 0);
    __syncthreads();
  }

  const int crow = row0 + wm * 64 + (lane >> 4) * 4;
  const int ccol = col0 + wn * 64 + (lane & 15);
  char* Cb = (char*)Cptr + (size_t)blockIdx.z * sC * (OUTBF ? 2 : 4);
  float bvv[4];
#pragma unroll
  for (int j = 0; j < 4; j++) bvv[j] = biasb[ccol + j * 16];
#pragma unroll
  for (int i = 0; i < 4; i++) {
#pragma unroll
    for (int r2 = 0; r2 < 4; r2++) {
      const size_t rowb = (size_t)(crow + i * 16 + r2) * ldc;
#pragma unroll
      for (int j = 0; j < 4; j++) {
        float v = acc[i][j][r2] + bvv[j];
        if (SILU) v = v / (1.0f + __expf(-v));
        const size_t cidx = rowb + ccol + j * 16;
        if (OUTBF)
          ((unsigned short*)Cb)[cidx] = f2bf(v);
        else
          ((float*)Cb)[cidx] = v;
      }
    }
  }
}

// ------ merged projections: z=0 text (K=768), z=1 image (K=1024); out cols z*1024 ------
__global__ __launch_bounds__(256) void proj2_kernel(
    const unsigned short* __restrict__ A0, const unsigned short* __restrict__ A1,
    const unsigned short* __restrict__ B0, const unsigned short* __restrict__ B1,
    const float* __restrict__ bias0, const float* __restrict__ bias1,
    unsigned short* __restrict__ Cptr) {
  __shared__ unsigned short Als[128 * 32];
  __shared__ unsigned short Bls[128 * 32];

  const int z = blockIdx.z;
  const unsigned short* Ab = z ? A1 : A0;
  const unsigned short* Bb = z ? B1 : B0;
  const float* biasb = z ? bias1 : bias0;
  const int K = z ? IDIM : TDIM;
  const int ldc = 2 * DDIM;

  const int gx = gridDim.x;
  const int nwg = gx * gridDim.y;
  const int orig = blockIdx.y * gx + blockIdx.x;
  const int q = nwg >> 3, r = nwg & 7;
  const int xcd = orig & 7, idx = orig >> 3;
  const int wgid = (xcd < r ? xcd * (q + 1) : r * (q + 1) + (xcd - r) * q) + idx;
  const int bx = wgid % gx, by = wgid / gx;

  const int tid = threadIdx.x;
  const int wave = tid >> 6, lane = tid & 63;
  const int row0 = by * 128, col0 = bx * 128;
  const int wm = wave >> 1, wn = wave & 1;
  f4 acc[4][4] = {};

  const int aoff = (wm * 64 + (lane & 15)) * 32 + (lane >> 4) * 8;
  const int boff = (wn * 64 + (lane & 15)) * 32 + (lane >> 4) * 8;

  const int L0 = tid, L1 = tid + 256;
  const size_t aofs0 = (size_t)(row0 + (L0 >> 2)) * K + (L0 & 3) * 8;
  const size_t aofs1 = (size_t)(row0 + (L1 >> 2)) * K + (L1 & 3) * 8;
  const size_t bofs0 = (size_t)(col0 + (L0 >> 2)) * K + (L0 & 3) * 8;
  const size_t bofs1 = (size_t)(col0 + (L1 >> 2)) * K + (L1 & 3) * 8;
  char* abase0 = (char*)Als + wave * 1024;
  char* abase1 = (char*)Als + 4096 + wave * 1024;
  char* bbase0 = (char*)Bls + wave * 1024;
  char* bbase1 = (char*)Bls + 4096 + wave * 1024;

  for (int k0 = 0; k0 < K; k0 += 32) {
    gload16(Ab + aofs0 + k0, abase0);
    gload16(Ab + aofs1 + k0, abase1);
    gload16(Bb + bofs0 + k0, bbase0);
    gload16(Bb + bofs1 + k0, bbase1);
    __syncthreads();
    short8 af[4], bfr[4];
#pragma unroll
    for (int i = 0; i < 4; i++) af[i] = *(const short8*)&Als[aoff + i * 512];
#pragma unroll
    for (int j = 0; j < 4; j++) bfr[j] = *(const short8*)&Bls[boff + j * 512];
#pragma unroll
    for (int i = 0; i < 4; i++)
#pragma unroll
      for (int j = 0; j < 4; j++)
        acc[i][j] = __builtin_amdgcn_mfma_f32_16x16x32_bf16(af[i], bfr[j], acc[i][j], 0, 0, 0);
    __syncthreads();
  }

  const int crow = row0 + wm * 64 + (lane >> 4) * 4;
  const int ccolL = col0 + wn * 64 + (lane & 15);
  const int ccol = z * DDIM + ccolL;
  float bvv[4];
#pragma unroll
  for (int j = 0; j < 4; j++) bvv[j] = biasb[ccolL + j * 16];
#pragma unroll
  for (int i = 0; i < 4; i++) {
#pragma unroll
    for (int r2 = 0; r2 < 4; r2++) {
      const size_t rowb = (size_t)(crow + i * 16 + r2) * ldc;
#pragma unroll
      for (int j = 0; j < 4; j++) {
        float v = acc[i][j][r2] + bvv[j];
        Cptr[rowb + ccol + j * 16] = f2bf(v);
      }
    }
  }
}

// ---------------- gating: logits = gh @ gW2 + gb2, softmax over 8 experts ----------------
__global__ __launch_bounds__(256) void gate_kernel(
    const unsigned short* __restrict__ gh, const float* __restrict__ gW2,
    const float* __restrict__ gb2, float* __restrict__ wout) {
  __shared__ float sW[NEXP * GHID];
  int tid = threadIdx.x;
  for (int i = tid; i < GHID * NEXP; i += 256) {
    int k = i >> 3, e = i & 7;
    sW[e * GHID + k] = gW2[i];
  }
  __syncthreads();
  int wave = tid >> 6, lane = tid & 63;
  int row = blockIdx.x * 4 + wave;
  float acc[NEXP] = {};
#pragma unroll
  for (int i = 0; i < 8; i++) {
    int k = lane + 64 * i;
    float x = bf2f(gh[(size_t)row * GHID + k]);
#pragma unroll
    for (int e = 0; e < NEXP; e++) acc[e] += x * sW[e * GHID + k];
  }
#pragma unroll
  for (int off = 32; off; off >>= 1)
#pragma unroll
    for (int e = 0; e < NEXP; e++) acc[e] += __shfl_xor(acc[e], off);
  float lg[NEXP], mx = -1e30f;
#pragma unroll
  for (int e = 0; e < NEXP; e++) { lg[e] = acc[e] + gb2[e]; mx = fmaxf(mx, lg[e]); }
  float s = 0.f;
#pragma unroll
  for (int e = 0; e < NEXP; e++) { lg[e] = __expf(lg[e] - mx); s += lg[e]; }
  if (lane < NEXP) wout[(size_t)row * NEXP + lane] = lg[lane] / s;
}

// ------- LayerNorm + gated sum over ALL 8 experts (bf16 o), write out once -------
__global__ __launch_bounds__(256) void ln_acc8_kernel(
    const unsigned short* __restrict__ o, const float* __restrict__ wgate,
    const float* __restrict__ ln_g, const float* __restrict__ ln_b,
    float* __restrict__ out, int row0) {
  int wave = threadIdx.x >> 6, lane = threadIdx.x & 63;
  int lrow = blockIdx.x * 4 + wave;
  int grow = row0 + lrow;
  float res[16];
#pragma unroll
  for (int u = 0; u < 16; u++) res[u] = 0.f;
#pragma unroll
  for (int e = 0; e < NEXP; e++) {
    const unsigned short* orow = o + (size_t)lrow * (NEXP * DDIM) + (size_t)e * DDIM;
    float xs[16];
    float s = 0.f, s2 = 0.f;
#pragma unroll
    for (int qq = 0; qq < 2; qq++) {
      short8 t = *(const short8*)&orow[qq * 512 + lane * 8];
#pragma unroll
      for (int u = 0; u < 8; u++) {
        float x = bf2f((unsigned short)t[u]);
        xs[qq * 8 + u] = x;
        s += x;
        s2 += x * x;
      }
    }
#pragma unroll
    for (int off = 32; off; off >>= 1) {
      s += __shfl_xor(s, off);
      s2 += __shfl_xor(s2, off);
    }
    const float inv = 1.0f / 1024.0f;
    float mu = s * inv;
    float var = s2 * inv - mu * mu;
    float rr = rsqrtf(var + 1e-5f);
    float wv = wgate[(size_t)grow * NEXP + e];
#pragma unroll
    for (int qq = 0; qq < 2; qq++) {
      int d = qq * 512 + lane * 8;
#pragma unroll
      for (int u = 0; u < 8; u++) {
        float gg = ln_g[(size_t)e * DDIM + d + u];
        float bb = ln_b[(size_t)e * DDIM + d + u];
        res[qq * 8 + u] += wv * ((xs[qq * 8 + u] - mu) * rr * gg + bb);
      }
    }
  }
  size_t rowbase = (size_t)grow * DDIM;
#pragma unroll
  for (int qq = 0; qq < 2; qq++) {
#pragma unroll
    for (int h = 0; h < 2; h++) {
      f4 t;
#pragma unroll
      for (int u = 0; u < 4; u++) t[u] = res[qq * 8 + h * 4 + u];
      *(f4*)&out[rowbase + qq * 512 + lane * 8 + h * 4] = t;
    }
  }
}

extern "C" void kernel_launch(void* const* d_in, const int* in_sizes, int n_in,
                              void* d_out, int out_size, void* d_ws, size_t ws_size,
                              hipStream_t stream) {
  const float* text  = (const float*)d_in[0];
  const float* image = (const float*)d_in[1];
  const float* Wt    = (const float*)d_in[2];
  const float* bt    = (const float*)d_in[3];
  const float* Wi    = (const float*)d_in[4];
  const float* bi    = (const float*)d_in[5];
  const float* eW1   = (const float*)d_in[6];
  const float* eb1   = (const float*)d_in[7];
  const float* eW2   = (const float*)d_in[8];
  const float* eb2   = (const float*)d_in[9];
  const float* ln_g  = (const float*)d_in[10];
  const float* ln_b  = (const float*)d_in[11];
  const float* gW1   = (const float*)d_in[12];
  const float* gb1   = (const float*)d_in[13];
  const float* gW2   = (const float*)d_in[14];
  const float* gb2   = (const float*)d_in[15];
  float* out = (float*)d_out;

  size_t off = 0;
  auto alloc = [&](size_t bytes) -> void* {
    void* p = (char*)d_ws + off;
    off += (bytes + 255) & ~(size_t)255;
    return p;
  };
  unsigned short* eW1T = (unsigned short*)alloc((size_t)NEXP * 2 * DDIM * DDIM * 2);
  unsigned short* eW2T = (unsigned short*)alloc((size_t)NEXP * DDIM * DDIM * 2);
  unsigned short* c_bf = (unsigned short*)alloc((size_t)NROWS * 2 * DDIM * 2);
  float* wgate         = (float*)alloc((size_t)NROWS * NEXP * 4);
  const size_t overlay0 = off;

  // setup overlay (dead after gate_kernel)
  unsigned short* text_bf = (unsigned short*)alloc((size_t)NROWS * TDIM * 2);
  unsigned short* img_bf  = (unsigned short*)alloc((size_t)NROWS * IDIM * 2);
  unsigned short* WtT     = (unsigned short*)alloc((size_t)TDIM * DDIM * 2);
  unsigned short* WiT     = (unsigned short*)alloc((size_t)IDIM * DDIM * 2);
  unsigned short* gW1T    = (unsigned short*)alloc((size_t)2 * DDIM * GHID * 2);
  unsigned short* gh_bf   = (unsigned short*)alloc((size_t)NROWS * GHID * 2);

  // expert-phase overlay: h (bf16) + o (bf16), 32KB/row; slab multiple of 256
  int slab = 8192;
  while (slab > 256 &&
         overlay0 + (size_t)slab * (size_t)(2 * NEXP * DDIM + 2 * NEXP * DDIM) > ws_size)
    slab >>= 1;
  unsigned short* h_slab = (unsigned short*)((char*)d_ws + overlay0);
  unsigned short* o_slab = (unsigned short*)((char*)d_ws + overlay0 +
                                             (size_t)slab * NEXP * DDIM * 2);

  // 1) activation casts
  cast_bf16_kernel<<<(NROWS * TDIM / 4 + 255) / 256, 256, 0, stream>>>(text, text_bf, NROWS * TDIM / 4);
  cast_bf16_kernel<<<(NROWS * IDIM / 4 + 255) / 256, 256, 0, stream>>>(image, img_bf, NROWS * IDIM / 4);

  // 2) weight transpose+cast (64x64 tiles)
  transpose_cast_kernel<<<dim3(DDIM / 64, TDIM / 64, 1), 256, 0, stream>>>(Wt, WtT, TDIM, DDIM);
  transpose_cast_kernel<<<dim3(DDIM / 64, IDIM / 64, 1), 256, 0, stream>>>(Wi, WiT, IDIM, DDIM);
  transpose_cast_kernel<<<dim3(GHID / 64, 2 * DDIM / 64, 1), 256, 0, stream>>>(gW1, gW1T, 2 * DDIM, GHID);
  transpose_cast_kernel<<<dim3(DDIM / 64, 2 * DDIM / 64, NEXP), 256, 0, stream>>>(eW1, eW1T, 2 * DDIM, DDIM);
  transpose_cast_kernel<<<dim3(DDIM / 64, DDIM / 64, NEXP), 256, 0, stream>>>(eW2, eW2T, DDIM, DDIM);

  // 3) merged projections into c = [ta | ia]
  proj2_kernel<<<dim3(DDIM / 128, NROWS / 128, 2), 256, 0, stream>>>(
      text_bf, img_bf, WtT, WiT, bt, bi, c_bf);

  // 4) gating hidden
  gemm_tn_kernel<1, 1><<<dim3(GHID / 128, NROWS / 128), 256, 0, stream>>>(
      c_bf, gW1T, gb1, gh_bf, 2 * DDIM, 2 * DDIM, 2 * DDIM, GHID, 0, 0, 0, 0);

  // 5) gate softmax
  gate_kernel<<<NROWS / 4, 256, 0, stream>>>(gh_bf, gW2, gb2, wgate);

  // 6) experts: slab over rows; W1 col-major XCD chunks, W2 row-major
  for (int r0 = 0; r0 < NROWS; r0 += slab) {
    gemm256_kernel<1, 1, 1><<<dim3(NEXP * DDIM / 256, slab / 256), 512, 0, stream>>>(
        c_bf + (size_t)r0 * 2 * DDIM, eW1T, eb1, h_slab,
        2 * DDIM, 2 * DDIM, 2 * DDIM, NEXP * DDIM, 0, 0, 0, 0);
    gemm256_kernel<0, 1, 0><<<dim3(DDIM / 256, slab / 256, NEXP), 512, 0, stream>>>(
        h_slab, eW2T, eb2, o_slab,
        DDIM, NEXP * DDIM, DDIM, NEXP * DDIM,
        (size_t)DDIM, (size_t)DDIM * DDIM, (size_t)DDIM, (size_t)DDIM);
    ln_acc8_kernel<<<slab / 4, 256, 0, stream>>>(o_slab, wgate, ln_g, ln_b, out, r0);
  }
}

// Round 16
// 657.007 us; speedup vs baseline: 1.0655x; 1.0655x over previous
//
#include <hip/hip_runtime.h>

#define NROWS 8192
#define TDIM 768
#define IDIM 1024
#define DDIM 1024
#define NEXP 8
#define GHID 512

typedef __attribute__((ext_vector_type(8))) short short8;
typedef __attribute__((ext_vector_type(4))) float f4;
typedef __attribute__((ext_vector_type(4))) unsigned short us4;

__device__ __forceinline__ unsigned short f2bf(float f) {
  union { float f; unsigned u; } v; v.f = f;
  unsigned r = v.u + 0x7FFF + ((v.u >> 16) & 1);
  return (unsigned short)(r >> 16);
}
__device__ __forceinline__ float bf2f(unsigned short u) {
  union { unsigned u; float f; } v; v.u = ((unsigned)u) << 16;
  return v.f;
}

__device__ __forceinline__ void gload16(const void* g, void* l) {
  __builtin_amdgcn_global_load_lds(
      (const __attribute__((address_space(1))) void*)g,
      (__attribute__((address_space(3))) void*)l, 16, 0, 0);
}

// ---------------- fp32 -> bf16 elementwise cast (vectorized) ----------------
__global__ __launch_bounds__(256) void cast_bf16_kernel(
    const float* __restrict__ src, unsigned short* __restrict__ dst, int n4) {
  int i = blockIdx.x * 256 + threadIdx.x;
  if (i < n4) {
    f4 v = ((const f4*)src)[i];
    us4 o;
    o[0] = f2bf(v[0]); o[1] = f2bf(v[1]); o[2] = f2bf(v[2]); o[3] = f2bf(v[3]);
    ((us4*)dst)[i] = o;
  }
}

// ------- fp32 [b][R][C] -> bf16 [b][C][R] transpose+cast, 64x64 tile, 16B stores ----
__global__ __launch_bounds__(256) void transpose_cast_kernel(
    const float* __restrict__ src, unsigned short* __restrict__ dst, int R, int C) {
  __shared__ float tile[64][65];
  size_t base = (size_t)blockIdx.z * R * C;
  int c0 = blockIdx.x * 64, r0 = blockIdx.y * 64;
  int tx = threadIdx.x & 63, ty = threadIdx.x >> 6;  // 64 x 4
#pragma unroll
  for (int j = 0; j < 64; j += 4)
    tile[ty + j][tx] = src[base + (size_t)(r0 + ty + j) * C + c0 + tx];
  __syncthreads();
  const int tid = threadIdx.x;
#pragma unroll
  for (int i = 0; i < 2; i++) {
    int row = i * 32 + (tid >> 3);
    int c8 = (tid & 7) * 8;
    short8 v;
#pragma unroll
    for (int u = 0; u < 8; u++) v[u] = (short)f2bf(tile[c8 + u][row]);
    *(short8*)&dst[base + (size_t)(c0 + row) * R + r0 + c8] = v;
  }
}

// ======== 256x256-tile bf16 TN GEMM, BK=64, 8 waves, 4-phase/tile (R13 best) ========
// T2 swizzle (0 conflicts). Counted vmcnt(4)/tile. T5 setprio. sched_barrier pin.
// Epilogue: n-innermost store order -> 4 consecutive stores fill one 128B line.
template <int SILU, int OUTBF, int COLMAJ>
__global__ __launch_bounds__(512, 1) void gemm256_kernel(
    const unsigned short* __restrict__ A, const unsigned short* __restrict__ BT,
    const float* __restrict__ bias, void* __restrict__ Cptr,
    int K, int lda, int ldb, int ldc,
    size_t sA, size_t sB, size_t sBias, size_t sC) {
  __shared__ __align__(16) char LDS[131072];

  const unsigned short* Ab = A + (size_t)blockIdx.z * sA;
  const unsigned short* Bb = BT + (size_t)blockIdx.z * sB;
  const float* biasb = bias + (size_t)blockIdx.z * sBias;

  const int gx = gridDim.x, gy = gridDim.y;
  const int nwg = gx * gy;
  const int orig = blockIdx.y * gx + blockIdx.x;
  const int q = nwg >> 3, r = nwg & 7;
  const int xcd = orig & 7, idx = orig >> 3;
  const int wgid = (xcd < r ? xcd * (q + 1) : r * (q + 1) + (xcd - r) * q) + idx;
  const int bx = COLMAJ ? (wgid / gy) : (wgid % gx);
  const int by = COLMAJ ? (wgid % gy) : (wgid / gx);

  const int tid = threadIdx.x;
  const int wave = tid >> 6, lane = tid & 63;
  const int wm = wave >> 2, wn = wave & 3;
  const int row0 = by * 256, col0 = bx * 256;

  f4 acc[8][4] = {};

  const int srow = tid >> 3;
  const int scolg = ((tid & 7) << 4) ^ (((tid >> 3) & 7) << 4);
  const size_t lda2 = (size_t)lda * 2, ldb2 = (size_t)ldb * 2;
  const char* Abytes = (const char*)Ab;
  const char* Bbytes = (const char*)Bb;
  const size_t aG = (size_t)(row0 + srow) * lda2 + scolg;
  const size_t bG = (size_t)(col0 + srow) * ldb2 + scolg;
  char* ldsw = LDS + wave * 1024;

  auto stageA0 = [&](int tt) {
    const size_t kb = (size_t)tt << 7;
    char* d = ldsw + ((tt & 1) << 16);
    gload16(Abytes + aG + kb, d);
    gload16(Abytes + aG + (size_t)64 * lda2 + kb, d + 8192);
  };
  auto stageA1 = [&](int tt) {
    const size_t kb = (size_t)tt << 7;
    char* d = ldsw + ((tt & 1) << 16);
    gload16(Abytes + aG + (size_t)128 * lda2 + kb, d + 16384);
    gload16(Abytes + aG + (size_t)192 * lda2 + kb, d + 24576);
  };
  auto stageB0 = [&](int tt) {
    const size_t kb = (size_t)tt << 7;
    char* d = ldsw + ((tt & 1) << 16) + 32768;
    gload16(Bbytes + bG + kb, d);
    gload16(Bbytes + bG + (size_t)64 * ldb2 + kb, d + 8192);
  };
  auto stageB1 = [&](int tt) {
    const size_t kb = (size_t)tt << 7;
    char* d = ldsw + ((tt & 1) << 16) + 32768;
    gload16(Bbytes + bG + (size_t)128 * ldb2 + kb, d + 16384);
    gload16(Bbytes + bG + (size_t)192 * ldb2 + kb, d + 24576);
  };

  const int aBase = (wm * 128 + (lane & 15)) * 128;
  const int bBase = 32768 + (wn * 64 + (lane & 15)) * 128;
  const int ck0 = ((lane >> 4) << 4) ^ ((lane & 7) << 4);

  const int NT = K >> 6;

  stageA0(0); stageA1(0); stageB0(0); stageB1(0);
  if (NT > 1) { stageB0(1); stageB1(1); }
  asm volatile("s_waitcnt vmcnt(4)" ::: "memory");
  __builtin_amdgcn_s_barrier();

  short8 bv[4][2];
  for (int t = 0; t < NT; t++) {
    const int aB = ((t & 1) << 16) + aBase;
    const int bB = ((t & 1) << 16) + bBase;

    // ---- P1: read all B + A m0,m1 (12 ds_read); stage A0(t+1) ----
    {
      short8 av[2][2];
#pragma unroll
      for (int n = 0; n < 4; n++)
#pragma unroll
        for (int kk = 0; kk < 2; kk++)
          bv[n][kk] = *(const short8*)(LDS + bB + n * 2048 + (ck0 ^ (kk << 6)));
#pragma unroll
      for (int m = 0; m < 2; m++)
#pragma unroll
        for (int kk = 0; kk < 2; kk++)
          av[m][kk] = *(const short8*)(LDS + aB + m * 2048 + (ck0 ^ (kk << 6)));
      if (t + 1 < NT) stageA0(t + 1);
      asm volatile("s_waitcnt lgkmcnt(8)" ::: "memory");
      __builtin_amdgcn_sched_barrier(0);
      __builtin_amdgcn_s_barrier();
      asm volatile("s_waitcnt lgkmcnt(0)" ::: "memory");
      __builtin_amdgcn_sched_barrier(0);
      __builtin_amdgcn_s_setprio(1);
#pragma unroll
      for (int kk = 0; kk < 2; kk++)
#pragma unroll
        for (int m = 0; m < 2; m++)
#pragma unroll
          for (int n = 0; n < 4; n++)
            acc[m][n] = __builtin_amdgcn_mfma_f32_16x16x32_bf16(av[m][kk], bv[n][kk], acc[m][n], 0, 0, 0);
      __builtin_amdgcn_s_setprio(0);
      __builtin_amdgcn_s_barrier();
    }

    // ---- P2: A m2,m3; stage A1(t+1) ---- P3: A m4,m5; stage B0(t+2) ----
    // ---- P4: A m6,m7; stage B1(t+2); vmcnt(4) after MFMA ----
#pragma unroll
    for (int ph = 1; ph < 4; ph++) {
      short8 av[2][2];
#pragma unroll
      for (int m = 0; m < 2; m++)
#pragma unroll
        for (int kk = 0; kk < 2; kk++)
          av[m][kk] = *(const short8*)(LDS + aB + (ph * 2 + m) * 2048 + (ck0 ^ (kk << 6)));
      if (ph == 1) {
        if (t + 1 < NT) stageA1(t + 1);
      } else if (ph == 2) {
        if (t + 2 < NT) stageB0(t + 2);
      } else {
        if (t + 2 < NT) stageB1(t + 2);
      }
      __builtin_amdgcn_sched_barrier(0);
      __builtin_amdgcn_s_barrier();
      asm volatile("s_waitcnt lgkmcnt(0)" ::: "memory");
      __builtin_amdgcn_sched_barrier(0);
      __builtin_amdgcn_s_setprio(1);
#pragma unroll
      for (int kk = 0; kk < 2; kk++)
#pragma unroll
        for (int m = 0; m < 2; m++)
#pragma unroll
          for (int n = 0; n < 4; n++)
            acc[ph * 2 + m][n] = __builtin_amdgcn_mfma_f32_16x16x32_bf16(av[m][kk], bv[n][kk], acc[ph * 2 + m][n], 0, 0, 0);
      __builtin_amdgcn_s_setprio(0);
      if (ph == 3) {
        if (t + 2 < NT) {
          asm volatile("s_waitcnt vmcnt(4)" ::: "memory");
        } else if (t + 1 < NT) {
          asm volatile("s_waitcnt vmcnt(0)" ::: "memory");
        }
      }
      __builtin_amdgcn_s_barrier();
    }
  }

  // epilogue: n innermost (write-combine)
  const int crow0 = row0 + wm * 128 + (lane >> 4) * 4;
  const int ccol0 = col0 + wn * 64 + (lane & 15);
  char* Cb = (char*)Cptr + (size_t)blockIdx.z * sC * (OUTBF ? 2 : 4);
  float bvv[4];
#pragma unroll
  for (int n = 0; n < 4; n++) bvv[n] = biasb[ccol0 + n * 16];
#pragma unroll
  for (int m = 0; m < 8; m++) {
#pragma unroll
    for (int r2 = 0; r2 < 4; r2++) {
      const size_t rowb = (size_t)(crow0 + m * 16 + r2) * ldc;
#pragma unroll
      for (int n = 0; n < 4; n++) {
        float v = acc[m][n][r2] + bvv[n];
        if (SILU) v = v / (1.0f + __expf(-v));
        const size_t cidx = rowb + ccol0 + n * 16;
        if (OUTBF) ((unsigned short*)Cb)[cidx] = f2bf(v);
        else       ((float*)Cb)[cidx] = v;
      }
    }
  }
}

// ---------------- 128x128 m97-structure GEMM (gating) ----------------
template <int SILU, int OUTBF>
__global__ __launch_bounds__(256) void gemm_tn_kernel(
    const unsigned short* __restrict__ A, const unsigned short* __restrict__ BT,
    const float* __restrict__ bias, void* __restrict__ Cptr,
    int K, int lda, int ldb, int ldc,
    size_t sA, size_t sB, size_t sBias, size_t sC) {
  __shared__ unsigned short Als[128 * 32];
  __shared__ unsigned short Bls[128 * 32];

  const unsigned short* Ab = A + (size_t)blockIdx.z * sA;
  const unsigned short* Bb = BT + (size_t)blockIdx.z * sB;
  const float* biasb = bias + (size_t)blockIdx.z * sBias;

  const int gx = gridDim.x;
  const int nwg = gx * gridDim.y;
  const int orig = blockIdx.y * gx + blockIdx.x;
  const int q = nwg >> 3, r = nwg & 7;
  const int xcd = orig & 7, idx = orig >> 3;
  const int wgid = (xcd < r ? xcd * (q + 1) : r * (q + 1) + (xcd - r) * q) + idx;
  const int bx = wgid % gx, by = wgid / gx;

  const int tid = threadIdx.x;
  const int wave = tid >> 6, lane = tid & 63;
  const int row0 = by * 128, col0 = bx * 128;
  const int wm = wave >> 1, wn = wave & 1;
  f4 acc[4][4] = {};

  const int aoff = (wm * 64 + (lane & 15)) * 32 + (lane >> 4) * 8;
  const int boff = (wn * 64 + (lane & 15)) * 32 + (lane >> 4) * 8;

  const int L0 = tid, L1 = tid + 256;
  const size_t aofs0 = (size_t)(row0 + (L0 >> 2)) * lda + (L0 & 3) * 8;
  const size_t aofs1 = (size_t)(row0 + (L1 >> 2)) * lda + (L1 & 3) * 8;
  const size_t bofs0 = (size_t)(col0 + (L0 >> 2)) * ldb + (L0 & 3) * 8;
  const size_t bofs1 = (size_t)(col0 + (L1 >> 2)) * ldb + (L1 & 3) * 8;
  char* abase0 = (char*)Als + wave * 1024;
  char* abase1 = (char*)Als + 4096 + wave * 1024;
  char* bbase0 = (char*)Bls + wave * 1024;
  char* bbase1 = (char*)Bls + 4096 + wave * 1024;

  for (int k0 = 0; k0 < K; k0 += 32) {
    gload16(Ab + aofs0 + k0, abase0);
    gload16(Ab + aofs1 + k0, abase1);
    gload16(Bb + bofs0 + k0, bbase0);
    gload16(Bb + bofs1 + k0, bbase1);
    __syncthreads();
    short8 af[4], bfr[4];
#pragma unroll
    for (int i = 0; i < 4; i++) af[i] = *(const short8*)&Als[aoff + i * 512];
#pragma unroll
    for (int j = 0; j < 4; j++) bfr[j] = *(const short8*)&Bls[boff + j * 512];
#pragma unroll
    for (int i = 0; i < 4; i++)
#pragma unroll
      for (int j = 0; j < 4; j++)
        acc[i][j] = __builtin_amdgcn_mfma_f32_16x16x32_bf16(af[i], bfr[j], acc[i][j], 0, 0, 0);
    __syncthreads();
  }

  const int crow = row0 + wm * 64 + (lane >> 4) * 4;
  const int ccol = col0 + wn * 64 + (lane & 15);
  char* Cb = (char*)Cptr + (size_t)blockIdx.z * sC * (OUTBF ? 2 : 4);
  float bvv[4];
#pragma unroll
  for (int j = 0; j < 4; j++) bvv[j] = biasb[ccol + j * 16];
#pragma unroll
  for (int i = 0; i < 4; i++) {
#pragma unroll
    for (int r2 = 0; r2 < 4; r2++) {
      const size_t rowb = (size_t)(crow + i * 16 + r2) * ldc;
#pragma unroll
      for (int j = 0; j < 4; j++) {
        float v = acc[i][j][r2] + bvv[j];
        if (SILU) v = v / (1.0f + __expf(-v));
        const size_t cidx = rowb + ccol + j * 16;
        if (OUTBF)
          ((unsigned short*)Cb)[cidx] = f2bf(v);
        else
          ((float*)Cb)[cidx] = v;
      }
    }
  }
}

// ------ merged projections: z=0 text (K=768), z=1 image (K=1024); out cols z*1024 ------
__global__ __launch_bounds__(256) void proj2_kernel(
    const unsigned short* __restrict__ A0, const unsigned short* __restrict__ A1,
    const unsigned short* __restrict__ B0, const unsigned short* __restrict__ B1,
    const float* __restrict__ bias0, const float* __restrict__ bias1,
    unsigned short* __restrict__ Cptr) {
  __shared__ unsigned short Als[128 * 32];
  __shared__ unsigned short Bls[128 * 32];

  const int z = blockIdx.z;
  const unsigned short* Ab = z ? A1 : A0;
  const unsigned short* Bb = z ? B1 : B0;
  const float* biasb = z ? bias1 : bias0;
  const int K = z ? IDIM : TDIM;
  const int ldc = 2 * DDIM;

  const int gx = gridDim.x;
  const int nwg = gx * gridDim.y;
  const int orig = blockIdx.y * gx + blockIdx.x;
  const int q = nwg >> 3, r = nwg & 7;
  const int xcd = orig & 7, idx = orig >> 3;
  const int wgid = (xcd < r ? xcd * (q + 1) : r * (q + 1) + (xcd - r) * q) + idx;
  const int bx = wgid % gx, by = wgid / gx;

  const int tid = threadIdx.x;
  const int wave = tid >> 6, lane = tid & 63;
  const int row0 = by * 128, col0 = bx * 128;
  const int wm = wave >> 1, wn = wave & 1;
  f4 acc[4][4] = {};

  const int aoff = (wm * 64 + (lane & 15)) * 32 + (lane >> 4) * 8;
  const int boff = (wn * 64 + (lane & 15)) * 32 + (lane >> 4) * 8;

  const int L0 = tid, L1 = tid + 256;
  const size_t aofs0 = (size_t)(row0 + (L0 >> 2)) * K + (L0 & 3) * 8;
  const size_t aofs1 = (size_t)(row0 + (L1 >> 2)) * K + (L1 & 3) * 8;
  const size_t bofs0 = (size_t)(col0 + (L0 >> 2)) * K + (L0 & 3) * 8;
  const size_t bofs1 = (size_t)(col0 + (L1 >> 2)) * K + (L1 & 3) * 8;
  char* abase0 = (char*)Als + wave * 1024;
  char* abase1 = (char*)Als + 4096 + wave * 1024;
  char* bbase0 = (char*)Bls + wave * 1024;
  char* bbase1 = (char*)Bls + 4096 + wave * 1024;

  for (int k0 = 0; k0 < K; k0 += 32) {
    gload16(Ab + aofs0 + k0, abase0);
    gload16(Ab + aofs1 + k0, abase1);
    gload16(Bb + bofs0 + k0, bbase0);
    gload16(Bb + bofs1 + k0, bbase1);
    __syncthreads();
    short8 af[4], bfr[4];
#pragma unroll
    for (int i = 0; i < 4; i++) af[i] = *(const short8*)&Als[aoff + i * 512];
#pragma unroll
    for (int j = 0; j < 4; j++) bfr[j] = *(const short8*)&Bls[boff + j * 512];
#pragma unroll
    for (int i = 0; i < 4; i++)
#pragma unroll
      for (int j = 0; j < 4; j++)
        acc[i][j] = __builtin_amdgcn_mfma_f32_16x16x32_bf16(af[i], bfr[j], acc[i][j], 0, 0, 0);
    __syncthreads();
  }

  const int crow = row0 + wm * 64 + (lane >> 4) * 4;
  const int ccolL = col0 + wn * 64 + (lane & 15);
  const int ccol = z * DDIM + ccolL;
  float bvv[4];
#pragma unroll
  for (int j = 0; j < 4; j++) bvv[j] = biasb[ccolL + j * 16];
#pragma unroll
  for (int i = 0; i < 4; i++) {
#pragma unroll
    for (int r2 = 0; r2 < 4; r2++) {
      const size_t rowb = (size_t)(crow + i * 16 + r2) * ldc;
#pragma unroll
      for (int j = 0; j < 4; j++) {
        float v = acc[i][j][r2] + bvv[j];
        Cptr[rowb + ccol + j * 16] = f2bf(v);
      }
    }
  }
}

// ---------------- gating: logits = gh @ gW2 + gb2, softmax over 8 experts ----------------
__global__ __launch_bounds__(256) void gate_kernel(
    const unsigned short* __restrict__ gh, const float* __restrict__ gW2,
    const float* __restrict__ gb2, float* __restrict__ wout) {
  __shared__ float sW[NEXP * GHID];
  int tid = threadIdx.x;
  for (int i = tid; i < GHID * NEXP; i += 256) {
    int k = i >> 3, e = i & 7;
    sW[e * GHID + k] = gW2[i];
  }
  __syncthreads();
  int wave = tid >> 6, lane = tid & 63;
  int row = blockIdx.x * 4 + wave;
  float acc[NEXP] = {};
#pragma unroll
  for (int i = 0; i < 8; i++) {
    int k = lane + 64 * i;
    float x = bf2f(gh[(size_t)row * GHID + k]);
#pragma unroll
    for (int e = 0; e < NEXP; e++) acc[e] += x * sW[e * GHID + k];
  }
#pragma unroll
  for (int off = 32; off; off >>= 1)
#pragma unroll
    for (int e = 0; e < NEXP; e++) acc[e] += __shfl_xor(acc[e], off);
  float lg[NEXP], mx = -1e30f;
#pragma unroll
  for (int e = 0; e < NEXP; e++) { lg[e] = acc[e] + gb2[e]; mx = fmaxf(mx, lg[e]); }
  float s = 0.f;
#pragma unroll
  for (int e = 0; e < NEXP; e++) { lg[e] = __expf(lg[e] - mx); s += lg[e]; }
  if (lane < NEXP) wout[(size_t)row * NEXP + lane] = lg[lane] / s;
}

// ------- LayerNorm + gated sum over ALL 8 experts (bf16 o), write out once -------
__global__ __launch_bounds__(256) void ln_acc8_kernel(
    const unsigned short* __restrict__ o, const float* __restrict__ wgate,
    const float* __restrict__ ln_g, const float* __restrict__ ln_b,
    float* __restrict__ out, int row0) {
  int wave = threadIdx.x >> 6, lane = threadIdx.x & 63;
  int lrow = blockIdx.x * 4 + wave;
  int grow = row0 + lrow;
  float res[16];
#pragma unroll
  for (int u = 0; u < 16; u++) res[u] = 0.f;
#pragma unroll
  for (int e = 0; e < NEXP; e++) {
    const unsigned short* orow = o + (size_t)lrow * (NEXP * DDIM) + (size_t)e * DDIM;
    float xs[16];
    float s = 0.f, s2 = 0.f;
#pragma unroll
    for (int qq = 0; qq < 2; qq++) {
      short8 t = *(const short8*)&orow[qq * 512 + lane * 8];
#pragma unroll
      for (int u = 0; u < 8; u++) {
        float x = bf2f((unsigned short)t[u]);
        xs[qq * 8 + u] = x;
        s += x;
        s2 += x * x;
      }
    }
#pragma unroll
    for (int off = 32; off; off >>= 1) {
      s += __shfl_xor(s, off);
      s2 += __shfl_xor(s2, off);
    }
    const float inv = 1.0f / 1024.0f;
    float mu = s * inv;
    float var = s2 * inv - mu * mu;
    float rr = rsqrtf(var + 1e-5f);
    float wv = wgate[(size_t)grow * NEXP + e];
#pragma unroll
    for (int qq = 0; qq < 2; qq++) {
      int d = qq * 512 + lane * 8;
#pragma unroll
      for (int u = 0; u < 8; u++) {
        float gg = ln_g[(size_t)e * DDIM + d + u];
        float bb = ln_b[(size_t)e * DDIM + d + u];
        res[qq * 8 + u] += wv * ((xs[qq * 8 + u] - mu) * rr * gg + bb);
      }
    }
  }
  size_t rowbase = (size_t)grow * DDIM;
#pragma unroll
  for (int qq = 0; qq < 2; qq++) {
#pragma unroll
    for (int h = 0; h < 2; h++) {
      f4 t;
#pragma unroll
      for (int u = 0; u < 4; u++) t[u] = res[qq * 8 + h * 4 + u];
      *(f4*)&out[rowbase + qq * 512 + lane * 8 + h * 4] = t;
    }
  }
}

extern "C" void kernel_launch(void* const* d_in, const int* in_sizes, int n_in,
                              void* d_out, int out_size, void* d_ws, size_t ws_size,
                              hipStream_t stream) {
  const float* text  = (const float*)d_in[0];
  const float* image = (const float*)d_in[1];
  const float* Wt    = (const float*)d_in[2];
  const float* bt    = (const float*)d_in[3];
  const float* Wi    = (const float*)d_in[4];
  const float* bi    = (const float*)d_in[5];
  const float* eW1   = (const float*)d_in[6];
  const float* eb1   = (const float*)d_in[7];
  const float* eW2   = (const float*)d_in[8];
  const float* eb2   = (const float*)d_in[9];
  const float* ln_g  = (const float*)d_in[10];
  const float* ln_b  = (const float*)d_in[11];
  const float* gW1   = (const float*)d_in[12];
  const float* gb1   = (const float*)d_in[13];
  const float* gW2   = (const float*)d_in[14];
  const float* gb2   = (const float*)d_in[15];
  float* out = (float*)d_out;

  size_t off = 0;
  auto alloc = [&](size_t bytes) -> void* {
    void* p = (char*)d_ws + off;
    off += (bytes + 255) & ~(size_t)255;
    return p;
  };
  unsigned short* eW1T = (unsigned short*)alloc((size_t)NEXP * 2 * DDIM * DDIM * 2);
  unsigned short* eW2T = (unsigned short*)alloc((size_t)NEXP * DDIM * DDIM * 2);
  unsigned short* c_bf = (unsigned short*)alloc((size_t)NROWS * 2 * DDIM * 2);
  float* wgate         = (float*)alloc((size_t)NROWS * NEXP * 4);
  const size_t overlay0 = off;

  // setup overlay (dead after gate_kernel)
  unsigned short* text_bf = (unsigned short*)alloc((size_t)NROWS * TDIM * 2);
  unsigned short* img_bf  = (unsigned short*)alloc((size_t)NROWS * IDIM * 2);
  unsigned short* WtT     = (unsigned short*)alloc((size_t)TDIM * DDIM * 2);
  unsigned short* WiT     = (unsigned short*)alloc((size_t)IDIM * DDIM * 2);
  unsigned short* gW1T    = (unsigned short*)alloc((size_t)2 * DDIM * GHID * 2);
  unsigned short* gh_bf   = (unsigned short*)alloc((size_t)NROWS * GHID * 2);

  // expert-phase overlay: h (bf16) + o (bf16), 32KB/row; slab multiple of 256
  int slab = 8192;
  while (slab > 256 &&
         overlay0 + (size_t)slab * (size_t)(2 * NEXP * DDIM + 2 * NEXP * DDIM) > ws_size)
    slab >>= 1;
  unsigned short* h_slab = (unsigned short*)((char*)d_ws + overlay0);
  unsigned short* o_slab = (unsigned short*)((char*)d_ws + overlay0 +
                                             (size_t)slab * NEXP * DDIM * 2);

  // 1) activation casts
  cast_bf16_kernel<<<(NROWS * TDIM / 4 + 255) / 256, 256, 0, stream>>>(text, text_bf, NROWS * TDIM / 4);
  cast_bf16_kernel<<<(NROWS * IDIM / 4 + 255) / 256, 256, 0, stream>>>(image, img_bf, NROWS * IDIM / 4);

  // 2) weight transpose+cast (64x64 tiles)
  transpose_cast_kernel<<<dim3(DDIM / 64, TDIM / 64, 1), 256, 0, stream>>>(Wt, WtT, TDIM, DDIM);
  transpose_cast_kernel<<<dim3(DDIM / 64, IDIM / 64, 1), 256, 0, stream>>>(Wi, WiT, IDIM, DDIM);
  transpose_cast_kernel<<<dim3(GHID / 64, 2 * DDIM / 64, 1), 256, 0, stream>>>(gW1, gW1T, 2 * DDIM, GHID);
  transpose_cast_kernel<<<dim3(DDIM / 64, 2 * DDIM / 64, NEXP), 256, 0, stream>>>(eW1, eW1T, 2 * DDIM, DDIM);
  transpose_cast_kernel<<<dim3(DDIM / 64, DDIM / 64, NEXP), 256, 0, stream>>>(eW2, eW2T, DDIM, DDIM);

  // 3) merged projections into c = [ta | ia]
  proj2_kernel<<<dim3(DDIM / 128, NROWS / 128, 2), 256, 0, stream>>>(
      text_bf, img_bf, WtT, WiT, bt, bi, c_bf);

  // 4) gating hidden
  gemm_tn_kernel<1, 1><<<dim3(GHID / 128, NROWS / 128), 256, 0, stream>>>(
      c_bf, gW1T, gb1, gh_bf, 2 * DDIM, 2 * DDIM, 2 * DDIM, GHID, 0, 0, 0, 0);

  // 5) gate softmax
  gate_kernel<<<NROWS / 4, 256, 0, stream>>>(gh_bf, gW2, gb2, wgate);

  // 6) experts: slab over rows; W1 col-major XCD chunks, W2 row-major
  for (int r0 = 0; r0 < NROWS; r0 += slab) {
    gemm256_kernel<1, 1, 1><<<dim3(NEXP * DDIM / 256, slab / 256), 512, 0, stream>>>(
        c_bf + (size_t)r0 * 2 * DDIM, eW1T, eb1, h_slab,
        2 * DDIM, 2 * DDIM, 2 * DDIM, NEXP * DDIM, 0, 0, 0, 0);
    gemm256_kernel<0, 1, 0><<<dim3(DDIM / 256, slab / 256, NEXP), 512, 0, stream>>>(
        h_slab, eW2T, eb2, o_slab,
        DDIM, NEXP * DDIM, DDIM, NEXP * DDIM,
        (size_t)DDIM, (size_t)DDIM * DDIM, (size_t)DDIM, (size_t)DDIM);
    ln_acc8_kernel<<<slab / 4, 256, 0, stream>>>(o_slab, wgate, ln_g, ln_b, out, r0);
  }
}

// Round 17
// 646.525 us; speedup vs baseline: 1.0827x; 1.0162x over previous
//
#include <hip/hip_runtime.h>

#define NROWS 8192
#define TDIM 768
#define IDIM 1024
#define DDIM 1024
#define NEXP 8
#define GHID 512

typedef __attribute__((ext_vector_type(8))) short short8;
typedef __attribute__((ext_vector_type(4))) float f4;
typedef __attribute__((ext_vector_type(4))) unsigned short us4;

__device__ __forceinline__ unsigned short f2bf(float f) {
  union { float f; unsigned u; } v; v.f = f;
  unsigned r = v.u + 0x7FFF + ((v.u >> 16) & 1);
  return (unsigned short)(r >> 16);
}
__device__ __forceinline__ float bf2f(unsigned short u) {
  union { unsigned u; float f; } v; v.u = ((unsigned)u) << 16;
  return v.f;
}

__device__ __forceinline__ void gload16(const void* g, void* l) {
  __builtin_amdgcn_global_load_lds(
      (const __attribute__((address_space(1))) void*)g,
      (__attribute__((address_space(3))) void*)l, 16, 0, 0);
}

// ---------------- fp32 -> bf16 elementwise cast (vectorized) ----------------
__global__ __launch_bounds__(256) void cast_bf16_kernel(
    const float* __restrict__ src, unsigned short* __restrict__ dst, int n4) {
  int i = blockIdx.x * 256 + threadIdx.x;
  if (i < n4) {
    f4 v = ((const f4*)src)[i];
    us4 o;
    o[0] = f2bf(v[0]); o[1] = f2bf(v[1]); o[2] = f2bf(v[2]); o[3] = f2bf(v[3]);
    ((us4*)dst)[i] = o;
  }
}

// ------- fp32 [b][R][C] -> bf16 [b][C][R] transpose+cast, 64x64 tile, 16B stores ----
__global__ __launch_bounds__(256) void transpose_cast_kernel(
    const float* __restrict__ src, unsigned short* __restrict__ dst, int R, int C) {
  __shared__ float tile[64][65];
  size_t base = (size_t)blockIdx.z * R * C;
  int c0 = blockIdx.x * 64, r0 = blockIdx.y * 64;
  int tx = threadIdx.x & 63, ty = threadIdx.x >> 6;  // 64 x 4
#pragma unroll
  for (int j = 0; j < 64; j += 4)
    tile[ty + j][tx] = src[base + (size_t)(r0 + ty + j) * C + c0 + tx];
  __syncthreads();
  const int tid = threadIdx.x;
#pragma unroll
  for (int i = 0; i < 2; i++) {
    int row = i * 32 + (tid >> 3);
    int c8 = (tid & 7) * 8;
    short8 v;
#pragma unroll
    for (int u = 0; u < 8; u++) v[u] = (short)f2bf(tile[c8 + u][row]);
    *(short8*)&dst[base + (size_t)(c0 + row) * R + r0 + c8] = v;
  }
}

// ======== 256x256-tile bf16 TN GEMM, BK=64, 8 waves, 4-phase/tile (R13 engine) ========
// T2 swizzle (0 conflicts). Counted vmcnt(4)/tile. T5 setprio. sched_barrier pin.
// Epilogue: n-innermost store order -> 4 consecutive stores fill one 128B line.
// COLMAJ: each XCD owns block-columns (B L2-resident) for single-z large-N GEMMs.
// ZXCD: 3D-linear remap pins expert (lin&7) to one XCD -> per-XCD B = 2MB L2-resident.
template <int SILU, int OUTBF, int COLMAJ, int ZXCD>
__global__ __launch_bounds__(512, 1) void gemm256_kernel(
    const unsigned short* __restrict__ A, const unsigned short* __restrict__ BT,
    const float* __restrict__ bias, void* __restrict__ Cptr,
    int K, int lda, int ldb, int ldc,
    size_t sA, size_t sB, size_t sBias, size_t sC) {
  __shared__ __align__(16) char LDS[131072];

  const int gx = gridDim.x, gy = gridDim.y;
  int zz, bx, by;
  if (ZXCD) {
    // full-grid linear id; expert = lin&7 so all of expert e's blocks share XCD e
    const int lin = (blockIdx.z * gy + blockIdx.y) * gx + blockIdx.x;
    zz = lin & 7;
    const int rest = lin >> 3;
    bx = rest % gx;
    by = rest / gx;
  } else {
    zz = blockIdx.z;
    const int nwg = gx * gy;
    const int orig = blockIdx.y * gx + blockIdx.x;
    const int q = nwg >> 3, r = nwg & 7;
    const int xcd = orig & 7, idx = orig >> 3;
    const int wgid = (xcd < r ? xcd * (q + 1) : r * (q + 1) + (xcd - r) * q) + idx;
    bx = COLMAJ ? (wgid / gy) : (wgid % gx);
    by = COLMAJ ? (wgid % gy) : (wgid / gx);
  }

  const unsigned short* Ab = A + (size_t)zz * sA;
  const unsigned short* Bb = BT + (size_t)zz * sB;
  const float* biasb = bias + (size_t)zz * sBias;

  const int tid = threadIdx.x;
  const int wave = tid >> 6, lane = tid & 63;
  const int wm = wave >> 2, wn = wave & 3;
  const int row0 = by * 256, col0 = bx * 256;

  f4 acc[8][4] = {};

  const int srow = tid >> 3;
  const int scolg = ((tid & 7) << 4) ^ (((tid >> 3) & 7) << 4);
  const size_t lda2 = (size_t)lda * 2, ldb2 = (size_t)ldb * 2;
  const char* Abytes = (const char*)Ab;
  const char* Bbytes = (const char*)Bb;
  const size_t aG = (size_t)(row0 + srow) * lda2 + scolg;
  const size_t bG = (size_t)(col0 + srow) * ldb2 + scolg;
  char* ldsw = LDS + wave * 1024;

  auto stageA0 = [&](int tt) {
    const size_t kb = (size_t)tt << 7;
    char* d = ldsw + ((tt & 1) << 16);
    gload16(Abytes + aG + kb, d);
    gload16(Abytes + aG + (size_t)64 * lda2 + kb, d + 8192);
  };
  auto stageA1 = [&](int tt) {
    const size_t kb = (size_t)tt << 7;
    char* d = ldsw + ((tt & 1) << 16);
    gload16(Abytes + aG + (size_t)128 * lda2 + kb, d + 16384);
    gload16(Abytes + aG + (size_t)192 * lda2 + kb, d + 24576);
  };
  auto stageB0 = [&](int tt) {
    const size_t kb = (size_t)tt << 7;
    char* d = ldsw + ((tt & 1) << 16) + 32768;
    gload16(Bbytes + bG + kb, d);
    gload16(Bbytes + bG + (size_t)64 * ldb2 + kb, d + 8192);
  };
  auto stageB1 = [&](int tt) {
    const size_t kb = (size_t)tt << 7;
    char* d = ldsw + ((tt & 1) << 16) + 32768;
    gload16(Bbytes + bG + (size_t)128 * ldb2 + kb, d + 16384);
    gload16(Bbytes + bG + (size_t)192 * ldb2 + kb, d + 24576);
  };

  const int aBase = (wm * 128 + (lane & 15)) * 128;
  const int bBase = 32768 + (wn * 64 + (lane & 15)) * 128;
  const int ck0 = ((lane >> 4) << 4) ^ ((lane & 7) << 4);

  const int NT = K >> 6;

  stageA0(0); stageA1(0); stageB0(0); stageB1(0);
  if (NT > 1) { stageB0(1); stageB1(1); }
  asm volatile("s_waitcnt vmcnt(4)" ::: "memory");
  __builtin_amdgcn_s_barrier();

  short8 bv[4][2];
  for (int t = 0; t < NT; t++) {
    const int aB = ((t & 1) << 16) + aBase;
    const int bB = ((t & 1) << 16) + bBase;

    // ---- P1: read all B + A m0,m1 (12 ds_read); stage A0(t+1) ----
    {
      short8 av[2][2];
#pragma unroll
      for (int n = 0; n < 4; n++)
#pragma unroll
        for (int kk = 0; kk < 2; kk++)
          bv[n][kk] = *(const short8*)(LDS + bB + n * 2048 + (ck0 ^ (kk << 6)));
#pragma unroll
      for (int m = 0; m < 2; m++)
#pragma unroll
        for (int kk = 0; kk < 2; kk++)
          av[m][kk] = *(const short8*)(LDS + aB + m * 2048 + (ck0 ^ (kk << 6)));
      if (t + 1 < NT) stageA0(t + 1);
      asm volatile("s_waitcnt lgkmcnt(8)" ::: "memory");
      __builtin_amdgcn_sched_barrier(0);
      __builtin_amdgcn_s_barrier();
      asm volatile("s_waitcnt lgkmcnt(0)" ::: "memory");
      __builtin_amdgcn_sched_barrier(0);
      __builtin_amdgcn_s_setprio(1);
#pragma unroll
      for (int kk = 0; kk < 2; kk++)
#pragma unroll
        for (int m = 0; m < 2; m++)
#pragma unroll
          for (int n = 0; n < 4; n++)
            acc[m][n] = __builtin_amdgcn_mfma_f32_16x16x32_bf16(av[m][kk], bv[n][kk], acc[m][n], 0, 0, 0);
      __builtin_amdgcn_s_setprio(0);
      __builtin_amdgcn_s_barrier();
    }

    // ---- P2: A m2,m3; stage A1(t+1) ---- P3: A m4,m5; stage B0(t+2) ----
    // ---- P4: A m6,m7; stage B1(t+2); vmcnt(4) after MFMA ----
#pragma unroll
    for (int ph = 1; ph < 4; ph++) {
      short8 av[2][2];
#pragma unroll
      for (int m = 0; m < 2; m++)
#pragma unroll
        for (int kk = 0; kk < 2; kk++)
          av[m][kk] = *(const short8*)(LDS + aB + (ph * 2 + m) * 2048 + (ck0 ^ (kk << 6)));
      if (ph == 1) {
        if (t + 1 < NT) stageA1(t + 1);
      } else if (ph == 2) {
        if (t + 2 < NT) stageB0(t + 2);
      } else {
        if (t + 2 < NT) stageB1(t + 2);
      }
      __builtin_amdgcn_sched_barrier(0);
      __builtin_amdgcn_s_barrier();
      asm volatile("s_waitcnt lgkmcnt(0)" ::: "memory");
      __builtin_amdgcn_sched_barrier(0);
      __builtin_amdgcn_s_setprio(1);
#pragma unroll
      for (int kk = 0; kk < 2; kk++)
#pragma unroll
        for (int m = 0; m < 2; m++)
#pragma unroll
          for (int n = 0; n < 4; n++)
            acc[ph * 2 + m][n] = __builtin_amdgcn_mfma_f32_16x16x32_bf16(av[m][kk], bv[n][kk], acc[ph * 2 + m][n], 0, 0, 0);
      __builtin_amdgcn_s_setprio(0);
      if (ph == 3) {
        if (t + 2 < NT) {
          asm volatile("s_waitcnt vmcnt(4)" ::: "memory");
        } else if (t + 1 < NT) {
          asm volatile("s_waitcnt vmcnt(0)" ::: "memory");
        }
      }
      __builtin_amdgcn_s_barrier();
    }
  }

  // epilogue: n innermost (write-combine)
  const int crow0 = row0 + wm * 128 + (lane >> 4) * 4;
  const int ccol0 = col0 + wn * 64 + (lane & 15);
  char* Cb = (char*)Cptr + (size_t)zz * sC * (OUTBF ? 2 : 4);
  float bvv[4];
#pragma unroll
  for (int n = 0; n < 4; n++) bvv[n] = biasb[ccol0 + n * 16];
#pragma unroll
  for (int m = 0; m < 8; m++) {
#pragma unroll
    for (int r2 = 0; r2 < 4; r2++) {
      const size_t rowb = (size_t)(crow0 + m * 16 + r2) * ldc;
#pragma unroll
      for (int n = 0; n < 4; n++) {
        float v = acc[m][n][r2] + bvv[n];
        if (SILU) v = v / (1.0f + __expf(-v));
        const size_t cidx = rowb + ccol0 + n * 16;
        if (OUTBF) ((unsigned short*)Cb)[cidx] = f2bf(v);
        else       ((float*)Cb)[cidx] = v;
      }
    }
  }
}

// ---------------- 128x128 m97-structure GEMM (gating) ----------------
template <int SILU, int OUTBF>
__global__ __launch_bounds__(256) void gemm_tn_kernel(
    const unsigned short* __restrict__ A, const unsigned short* __restrict__ BT,
    const float* __restrict__ bias, void* __restrict__ Cptr,
    int K, int lda, int ldb, int ldc,
    size_t sA, size_t sB, size_t sBias, size_t sC) {
  __shared__ unsigned short Als[128 * 32];
  __shared__ unsigned short Bls[128 * 32];

  const unsigned short* Ab = A + (size_t)blockIdx.z * sA;
  const unsigned short* Bb = BT + (size_t)blockIdx.z * sB;
  const float* biasb = bias + (size_t)blockIdx.z * sBias;

  const int gx = gridDim.x;
  const int nwg = gx * gridDim.y;
  const int orig = blockIdx.y * gx + blockIdx.x;
  const int q = nwg >> 3, r = nwg & 7;
  const int xcd = orig & 7, idx = orig >> 3;
  const int wgid = (xcd < r ? xcd * (q + 1) : r * (q + 1) + (xcd - r) * q) + idx;
  const int bx = wgid % gx, by = wgid / gx;

  const int tid = threadIdx.x;
  const int wave = tid >> 6, lane = tid & 63;
  const int row0 = by * 128, col0 = bx * 128;
  const int wm = wave >> 1, wn = wave & 1;
  f4 acc[4][4] = {};

  const int aoff = (wm * 64 + (lane & 15)) * 32 + (lane >> 4) * 8;
  const int boff = (wn * 64 + (lane & 15)) * 32 + (lane >> 4) * 8;

  const int L0 = tid, L1 = tid + 256;
  const size_t aofs0 = (size_t)(row0 + (L0 >> 2)) * lda + (L0 & 3) * 8;
  const size_t aofs1 = (size_t)(row0 + (L1 >> 2)) * lda + (L1 & 3) * 8;
  const size_t bofs0 = (size_t)(col0 + (L0 >> 2)) * ldb + (L0 & 3) * 8;
  const size_t bofs1 = (size_t)(col0 + (L1 >> 2)) * ldb + (L1 & 3) * 8;
  char* abase0 = (char*)Als + wave * 1024;
  char* abase1 = (char*)Als + 4096 + wave * 1024;
  char* bbase0 = (char*)Bls + wave * 1024;
  char* bbase1 = (char*)Bls + 4096 + wave * 1024;

  for (int k0 = 0; k0 < K; k0 += 32) {
    gload16(Ab + aofs0 + k0, abase0);
    gload16(Ab + aofs1 + k0, abase1);
    gload16(Bb + bofs0 + k0, bbase0);
    gload16(Bb + bofs1 + k0, bbase1);
    __syncthreads();
    short8 af[4], bfr[4];
#pragma unroll
    for (int i = 0; i < 4; i++) af[i] = *(const short8*)&Als[aoff + i * 512];
#pragma unroll
    for (int j = 0; j < 4; j++) bfr[j] = *(const short8*)&Bls[boff + j * 512];
#pragma unroll
    for (int i = 0; i < 4; i++)
#pragma unroll
      for (int j = 0; j < 4; j++)
        acc[i][j] = __builtin_amdgcn_mfma_f32_16x16x32_bf16(af[i], bfr[j], acc[i][j], 0, 0, 0);
    __syncthreads();
  }

  const int crow = row0 + wm * 64 + (lane >> 4) * 4;
  const int ccol = col0 + wn * 64 + (lane & 15);
  char* Cb = (char*)Cptr + (size_t)blockIdx.z * sC * (OUTBF ? 2 : 4);
  float bvv[4];
#pragma unroll
  for (int j = 0; j < 4; j++) bvv[j] = biasb[ccol + j * 16];
#pragma unroll
  for (int i = 0; i < 4; i++) {
#pragma unroll
    for (int r2 = 0; r2 < 4; r2++) {
      const size_t rowb = (size_t)(crow + i * 16 + r2) * ldc;
#pragma unroll
      for (int j = 0; j < 4; j++) {
        float v = acc[i][j][r2] + bvv[j];
        if (SILU) v = v / (1.0f + __expf(-v));
        const size_t cidx = rowb + ccol + j * 16;
        if (OUTBF)
          ((unsigned short*)Cb)[cidx] = f2bf(v);
        else
          ((float*)Cb)[cidx] = v;
      }
    }
  }
}

// ------ merged projections: z=0 text (K=768), z=1 image (K=1024); out cols z*1024 ------
__global__ __launch_bounds__(256) void proj2_kernel(
    const unsigned short* __restrict__ A0, const unsigned short* __restrict__ A1,
    const unsigned short* __restrict__ B0, const unsigned short* __restrict__ B1,
    const float* __restrict__ bias0, const float* __restrict__ bias1,
    unsigned short* __restrict__ Cptr) {
  __shared__ unsigned short Als[128 * 32];
  __shared__ unsigned short Bls[128 * 32];

  const int z = blockIdx.z;
  const unsigned short* Ab = z ? A1 : A0;
  const unsigned short* Bb = z ? B1 : B0;
  const float* biasb = z ? bias1 : bias0;
  const int K = z ? IDIM : TDIM;
  const int ldc = 2 * DDIM;

  const int gx = gridDim.x;
  const int nwg = gx * gridDim.y;
  const int orig = blockIdx.y * gx + blockIdx.x;
  const int q = nwg >> 3, r = nwg & 7;
  const int xcd = orig & 7, idx = orig >> 3;
  const int wgid = (xcd < r ? xcd * (q + 1) : r * (q + 1) + (xcd - r) * q) + idx;
  const int bx = wgid % gx, by = wgid / gx;

  const int tid = threadIdx.x;
  const int wave = tid >> 6, lane = tid & 63;
  const int row0 = by * 128, col0 = bx * 128;
  const int wm = wave >> 1, wn = wave & 1;
  f4 acc[4][4] = {};

  const int aoff = (wm * 64 + (lane & 15)) * 32 + (lane >> 4) * 8;
  const int boff = (wn * 64 + (lane & 15)) * 32 + (lane >> 4) * 8;

  const int L0 = tid, L1 = tid + 256;
  const size_t aofs0 = (size_t)(row0 + (L0 >> 2)) * K + (L0 & 3) * 8;
  const size_t aofs1 = (size_t)(row0 + (L1 >> 2)) * K + (L1 & 3) * 8;
  const size_t bofs0 = (size_t)(col0 + (L0 >> 2)) * K + (L0 & 3) * 8;
  const size_t bofs1 = (size_t)(col0 + (L1 >> 2)) * K + (L1 & 3) * 8;
  char* abase0 = (char*)Als + wave * 1024;
  char* abase1 = (char*)Als + 4096 + wave * 1024;
  char* bbase0 = (char*)Bls + wave * 1024;
  char* bbase1 = (char*)Bls + 4096 + wave * 1024;

  for (int k0 = 0; k0 < K; k0 += 32) {
    gload16(Ab + aofs0 + k0, abase0);
    gload16(Ab + aofs1 + k0, abase1);
    gload16(Bb + bofs0 + k0, bbase0);
    gload16(Bb + bofs1 + k0, bbase1);
    __syncthreads();
    short8 af[4], bfr[4];
#pragma unroll
    for (int i = 0; i < 4; i++) af[i] = *(const short8*)&Als[aoff + i * 512];
#pragma unroll
    for (int j = 0; j < 4; j++) bfr[j] = *(const short8*)&Bls[boff + j * 512];
#pragma unroll
    for (int i = 0; i < 4; i++)
#pragma unroll
      for (int j = 0; j < 4; j++)
        acc[i][j] = __builtin_amdgcn_mfma_f32_16x16x32_bf16(af[i], bfr[j], acc[i][j], 0, 0, 0);
    __syncthreads();
  }

  const int crow = row0 + wm * 64 + (lane >> 4) * 4;
  const int ccolL = col0 + wn * 64 + (lane & 15);
  const int ccol = z * DDIM + ccolL;
  float bvv[4];
#pragma unroll
  for (int j = 0; j < 4; j++) bvv[j] = biasb[ccolL + j * 16];
#pragma unroll
  for (int i = 0; i < 4; i++) {
#pragma unroll
    for (int r2 = 0; r2 < 4; r2++) {
      const size_t rowb = (size_t)(crow + i * 16 + r2) * ldc;
#pragma unroll
      for (int j = 0; j < 4; j++) {
        float v = acc[i][j][r2] + bvv[j];
        Cptr[rowb + ccol + j * 16] = f2bf(v);
      }
    }
  }
}

// ---------------- gating: logits = gh @ gW2 + gb2, softmax over 8 experts ----------------
__global__ __launch_bounds__(256) void gate_kernel(
    const unsigned short* __restrict__ gh, const float* __restrict__ gW2,
    const float* __restrict__ gb2, float* __restrict__ wout) {
  __shared__ float sW[NEXP * GHID];
  int tid = threadIdx.x;
  for (int i = tid; i < GHID * NEXP; i += 256) {
    int k = i >> 3, e = i & 7;
    sW[e * GHID + k] = gW2[i];
  }
  __syncthreads();
  int wave = tid >> 6, lane = tid & 63;
  int row = blockIdx.x * 4 + wave;
  float acc[NEXP] = {};
#pragma unroll
  for (int i = 0; i < 8; i++) {
    int k = lane + 64 * i;
    float x = bf2f(gh[(size_t)row * GHID + k]);
#pragma unroll
    for (int e = 0; e < NEXP; e++) acc[e] += x * sW[e * GHID + k];
  }
#pragma unroll
  for (int off = 32; off; off >>= 1)
#pragma unroll
    for (int e = 0; e < NEXP; e++) acc[e] += __shfl_xor(acc[e], off);
  float lg[NEXP], mx = -1e30f;
#pragma unroll
  for (int e = 0; e < NEXP; e++) { lg[e] = acc[e] + gb2[e]; mx = fmaxf(mx, lg[e]); }
  float s = 0.f;
#pragma unroll
  for (int e = 0; e < NEXP; e++) { lg[e] = __expf(lg[e] - mx); s += lg[e]; }
  if (lane < NEXP) wout[(size_t)row * NEXP + lane] = lg[lane] / s;
}

// ------- LayerNorm + gated sum over ALL 8 experts (bf16 o), write out once -------
__global__ __launch_bounds__(256) void ln_acc8_kernel(
    const unsigned short* __restrict__ o, const float* __restrict__ wgate,
    const float* __restrict__ ln_g, const float* __restrict__ ln_b,
    float* __restrict__ out, int row0) {
  int wave = threadIdx.x >> 6, lane = threadIdx.x & 63;
  int lrow = blockIdx.x * 4 + wave;
  int grow = row0 + lrow;
  float res[16];
#pragma unroll
  for (int u = 0; u < 16; u++) res[u] = 0.f;
#pragma unroll
  for (int e = 0; e < NEXP; e++) {
    const unsigned short* orow = o + (size_t)lrow * (NEXP * DDIM) + (size_t)e * DDIM;
    float xs[16];
    float s = 0.f, s2 = 0.f;
#pragma unroll
    for (int qq = 0; qq < 2; qq++) {
      short8 t = *(const short8*)&orow[qq * 512 + lane * 8];
#pragma unroll
      for (int u = 0; u < 8; u++) {
        float x = bf2f((unsigned short)t[u]);
        xs[qq * 8 + u] = x;
        s += x;
        s2 += x * x;
      }
    }
#pragma unroll
    for (int off = 32; off; off >>= 1) {
      s += __shfl_xor(s, off);
      s2 += __shfl_xor(s2, off);
    }
    const float inv = 1.0f / 1024.0f;
    float mu = s * inv;
    float var = s2 * inv - mu * mu;
    float rr = rsqrtf(var + 1e-5f);
    float wv = wgate[(size_t)grow * NEXP + e];
#pragma unroll
    for (int qq = 0; qq < 2; qq++) {
      int d = qq * 512 + lane * 8;
#pragma unroll
      for (int u = 0; u < 8; u++) {
        float gg = ln_g[(size_t)e * DDIM + d + u];
        float bb = ln_b[(size_t)e * DDIM + d + u];
        res[qq * 8 + u] += wv * ((xs[qq * 8 + u] - mu) * rr * gg + bb);
      }
    }
  }
  size_t rowbase = (size_t)grow * DDIM;
#pragma unroll
  for (int qq = 0; qq < 2; qq++) {
#pragma unroll
    for (int h = 0; h < 2; h++) {
      f4 t;
#pragma unroll
      for (int u = 0; u < 4; u++) t[u] = res[qq * 8 + h * 4 + u];
      *(f4*)&out[rowbase + qq * 512 + lane * 8 + h * 4] = t;
    }
  }
}

extern "C" void kernel_launch(void* const* d_in, const int* in_sizes, int n_in,
                              void* d_out, int out_size, void* d_ws, size_t ws_size,
                              hipStream_t stream) {
  const float* text  = (const float*)d_in[0];
  const float* image = (const float*)d_in[1];
  const float* Wt    = (const float*)d_in[2];
  const float* bt    = (const float*)d_in[3];
  const float* Wi    = (const float*)d_in[4];
  const float* bi    = (const float*)d_in[5];
  const float* eW1   = (const float*)d_in[6];
  const float* eb1   = (const float*)d_in[7];
  const float* eW2   = (const float*)d_in[8];
  const float* eb2   = (const float*)d_in[9];
  const float* ln_g  = (const float*)d_in[10];
  const float* ln_b  = (const float*)d_in[11];
  const float* gW1   = (const float*)d_in[12];
  const float* gb1   = (const float*)d_in[13];
  const float* gW2   = (const float*)d_in[14];
  const float* gb2   = (const float*)d_in[15];
  float* out = (float*)d_out;

  size_t off = 0;
  auto alloc = [&](size_t bytes) -> void* {
    void* p = (char*)d_ws + off;
    off += (bytes + 255) & ~(size_t)255;
    return p;
  };
  unsigned short* eW1T = (unsigned short*)alloc((size_t)NEXP * 2 * DDIM * DDIM * 2);
  unsigned short* eW2T = (unsigned short*)alloc((size_t)NEXP * DDIM * DDIM * 2);
  unsigned short* c_bf = (unsigned short*)alloc((size_t)NROWS * 2 * DDIM * 2);
  float* wgate         = (float*)alloc((size_t)NROWS * NEXP * 4);
  const size_t overlay0 = off;

  // setup overlay (dead after gate_kernel)
  unsigned short* text_bf = (unsigned short*)alloc((size_t)NROWS * TDIM * 2);
  unsigned short* img_bf  = (unsigned short*)alloc((size_t)NROWS * IDIM * 2);
  unsigned short* WtT     = (unsigned short*)alloc((size_t)TDIM * DDIM * 2);
  unsigned short* WiT     = (unsigned short*)alloc((size_t)IDIM * DDIM * 2);
  unsigned short* gW1T    = (unsigned short*)alloc((size_t)2 * DDIM * GHID * 2);
  unsigned short* gh_bf   = (unsigned short*)alloc((size_t)NROWS * GHID * 2);

  // expert-phase overlay: h (bf16) + o (bf16), 32KB/row; slab multiple of 256
  int slab = 8192;
  while (slab > 256 &&
         overlay0 + (size_t)slab * (size_t)(2 * NEXP * DDIM + 2 * NEXP * DDIM) > ws_size)
    slab >>= 1;
  unsigned short* h_slab = (unsigned short*)((char*)d_ws + overlay0);
  unsigned short* o_slab = (unsigned short*)((char*)d_ws + overlay0 +
                                             (size_t)slab * NEXP * DDIM * 2);

  // 1) activation casts
  cast_bf16_kernel<<<(NROWS * TDIM / 4 + 255) / 256, 256, 0, stream>>>(text, text_bf, NROWS * TDIM / 4);
  cast_bf16_kernel<<<(NROWS * IDIM / 4 + 255) / 256, 256, 0, stream>>>(image, img_bf, NROWS * IDIM / 4);

  // 2) weight transpose+cast (64x64 tiles)
  transpose_cast_kernel<<<dim3(DDIM / 64, TDIM / 64, 1), 256, 0, stream>>>(Wt, WtT, TDIM, DDIM);
  transpose_cast_kernel<<<dim3(DDIM / 64, IDIM / 64, 1), 256, 0, stream>>>(Wi, WiT, IDIM, DDIM);
  transpose_cast_kernel<<<dim3(GHID / 64, 2 * DDIM / 64, 1), 256, 0, stream>>>(gW1, gW1T, 2 * DDIM, GHID);
  transpose_cast_kernel<<<dim3(DDIM / 64, 2 * DDIM / 64, NEXP), 256, 0, stream>>>(eW1, eW1T, 2 * DDIM, DDIM);
  transpose_cast_kernel<<<dim3(DDIM / 64, DDIM / 64, NEXP), 256, 0, stream>>>(eW2, eW2T, DDIM, DDIM);

  // 3) merged projections into c = [ta | ia]
  proj2_kernel<<<dim3(DDIM / 128, NROWS / 128, 2), 256, 0, stream>>>(
      text_bf, img_bf, WtT, WiT, bt, bi, c_bf);

  // 4) gating hidden
  gemm_tn_kernel<1, 1><<<dim3(GHID / 128, NROWS / 128), 256, 0, stream>>>(
      c_bf, gW1T, gb1, gh_bf, 2 * DDIM, 2 * DDIM, 2 * DDIM, GHID, 0, 0, 0, 0);

  // 5) gate softmax
  gate_kernel<<<NROWS / 4, 256, 0, stream>>>(gh_bf, gW2, gb2, wgate);

  // 6) experts: W1 col-major XCD chunks; W2 z-pinned XCD mapping (B L2-resident)
  for (int r0 = 0; r0 < NROWS; r0 += slab) {
    gemm256_kernel<1, 1, 1, 0><<<dim3(NEXP * DDIM / 256, slab / 256), 512, 0, stream>>>(
        c_bf + (size_t)r0 * 2 * DDIM, eW1T, eb1, h_slab,
        2 * DDIM, 2 * DDIM, 2 * DDIM, NEXP * DDIM, 0, 0, 0, 0);
    gemm256_kernel<0, 1, 0, 1><<<dim3(DDIM / 256, slab / 256, NEXP), 512, 0, stream>>>(
        h_slab, eW2T, eb2, o_slab,
        DDIM, NEXP * DDIM, DDIM, NEXP * DDIM,
        (size_t)DDIM, (size_t)DDIM * DDIM, (size_t)DDIM, (size_t)DDIM);
    ln_acc8_kernel<<<slab / 4, 256, 0, stream>>>(o_slab, wgate, ln_g, ln_b, out, r0);
  }
}